// Round 1
// baseline (522672.754 us; speedup 1.0000x reference)
//
#include <hip/hip_runtime.h>
#include <math.h>

// LSTM T=32768, B=1, I=128, H=512. Persistent-kernel design:
// 32 WGs x 512 threads, W_hh/W_ih register-resident, per-step global barrier.
// WG w owns h[16w..16w+16) and gate rows {g*512 + 16w + r : g<4, r<16}.
// Thread (rl=tid>>3, j=tid&7): row rl of the WG's 64 rows, K-chunk j
// (64 W_hh weights, 16 W_ih weights). 8-lane shuffle reduce per row.

#define T_SEQ 32768
#define HID   512
#define INP   128
#define NWG   32
#define NTH   512
#define HSL   16    // h elements per WG
#define KW    64    // W_hh weights per thread
#define KX    16    // W_ih weights per thread

__global__ void __launch_bounds__(NTH, 2) lstm_persist(
    const float* __restrict__ x,
    const float* __restrict__ W_ih,
    const float* __restrict__ W_hh,
    const float* __restrict__ b_ih,
    const float* __restrict__ b_hh,
    const float* __restrict__ W1,
    const float* __restrict__ Wout,
    unsigned int* __restrict__ ctr,
    float* __restrict__ hbuf,        // 2 * 512 floats, ping-pong
    float* __restrict__ out)         // pre-initialized to b_eff
{
    const int w   = blockIdx.x;
    const int tid = threadIdx.x;
    const int rl  = tid >> 3;        // 0..63 local gate row
    const int j   = tid & 7;         // K-chunk
    const int gblk   = rl >> 4;      // 0..3 (i,f,g,o)
    const int within = rl & 15;
    const int grow   = gblk * HID + w * HSL + within;

    __shared__ float gate_lds[64];

    // ---- load weights into registers (once) ----
    float wih[KX];
#pragma unroll
    for (int k = 0; k < KX; ++k) wih[k] = W_ih[grow * INP + j * KX + k];
    float whh[KW];
#pragma unroll
    for (int k = 0; k < KW; ++k) whh[k] = W_hh[grow * HID + j * KW + k];
    const float brow = b_ih[grow] + b_hh[grow];

    // fused output projection vector: w_eff[col] = sum_p Wout[p] * W1[p][col]
    float weff = 0.0f;
    if (tid < HSL) {
        const int col = w * HSL + tid;
        for (int p = 0; p < 25; ++p) weff += Wout[p] * W1[p * HID + col];
    }

    // ---- init h_{-1} = 0 in buffer 0, then global arrival (+1 per WG) ----
    if (tid < HSL)
        __hip_atomic_store(&hbuf[w * HSL + tid], 0.0f,
                           __ATOMIC_RELAXED, __HIP_MEMORY_SCOPE_AGENT);
    __threadfence();
    __syncthreads();
    if (tid == 0)
        __hip_atomic_fetch_add(ctr, 1u, __ATOMIC_RELEASE, __HIP_MEMORY_SCOPE_AGENT);

    float c = 0.0f;

    // prefetch x_0 chunk
    float xa[KX];
#pragma unroll
    for (int k = 0; k < KX; ++k) xa[k] = x[j * KX + k];

    for (int t = 0; t < T_SEQ; ++t) {
        // ---- barrier: wait until all WGs published h_{t-1} ----
        const unsigned int target = (unsigned int)(NWG * (t + 1));
        while (__hip_atomic_load(ctr, __ATOMIC_ACQUIRE, __HIP_MEMORY_SCOPE_AGENT) < target) {
            __builtin_amdgcn_s_sleep(1);
        }
        const float* hb = hbuf + (t & 1) * HID;

        float a0 = 0.0f, a1 = 0.0f, a2 = 0.0f, a3 = 0.0f;

        // x contribution (x_t already in registers)
#pragma unroll
        for (int k = 0; k < KX; k += 4) {
            a0 += wih[k + 0] * xa[k + 0];
            a1 += wih[k + 1] * xa[k + 1];
            a2 += wih[k + 2] * xa[k + 2];
            a3 += wih[k + 3] * xa[k + 3];
        }

        // h gather (coherent agent-scope loads) + dot
#pragma unroll
        for (int k = 0; k < KW; k += 4) {
            float h0 = __hip_atomic_load(&hb[j * KW + k + 0], __ATOMIC_RELAXED, __HIP_MEMORY_SCOPE_AGENT);
            float h1 = __hip_atomic_load(&hb[j * KW + k + 1], __ATOMIC_RELAXED, __HIP_MEMORY_SCOPE_AGENT);
            float h2 = __hip_atomic_load(&hb[j * KW + k + 2], __ATOMIC_RELAXED, __HIP_MEMORY_SCOPE_AGENT);
            float h3 = __hip_atomic_load(&hb[j * KW + k + 3], __ATOMIC_RELAXED, __HIP_MEMORY_SCOPE_AGENT);
            a0 += whh[k + 0] * h0;
            a1 += whh[k + 1] * h1;
            a2 += whh[k + 2] * h2;
            a3 += whh[k + 3] * h3;
        }

        // prefetch x_{t+1} for next step (off critical path)
        const int tn = (t + 1 < T_SEQ) ? (t + 1) : t;
#pragma unroll
        for (int k = 0; k < KX; ++k) xa[k] = x[tn * INP + j * KX + k];

        float acc = (a0 + a1) + (a2 + a3);
        acc += __shfl_xor(acc, 1);
        acc += __shfl_xor(acc, 2);
        acc += __shfl_xor(acc, 4);
        if (j == 0) gate_lds[rl] = acc + brow;
        __syncthreads();

        if (tid < HSL) {
            const float ig = gate_lds[tid];
            const float fg = gate_lds[16 + tid];
            const float gg = gate_lds[32 + tid];
            const float og = gate_lds[48 + tid];
            const float iv = 1.0f / (1.0f + expf(-ig));
            const float fv = 1.0f / (1.0f + expf(-fg));
            const float gv = tanhf(gg);
            const float ov = 1.0f / (1.0f + expf(-og));
            c = fv * c + iv * gv;
            const float hv = ov * tanhf(c);
            __hip_atomic_store(&hbuf[((t + 1) & 1) * HID + w * HSL + tid], hv,
                               __ATOMIC_RELAXED, __HIP_MEMORY_SCOPE_AGENT);
            // fused output projection partial: dot(h_slice, w_eff_slice)
            float pd = hv * weff;
            pd += __shfl_xor(pd, 1);
            pd += __shfl_xor(pd, 2);
            pd += __shfl_xor(pd, 4);
            pd += __shfl_xor(pd, 8);
            if (tid == 0) atomicAdd(&out[t], pd);
        }
        __threadfence();
        __syncthreads();
        if (tid == 0)
            __hip_atomic_fetch_add(ctr, 1u, __ATOMIC_RELEASE, __HIP_MEMORY_SCOPE_AGENT);
    }
}

// out[t] starts at b_eff = dot(b1, Wout); persistent kernel atomicAdds the
// h-projection partials on top.
__global__ void init_out(const float* __restrict__ b1,
                         const float* __restrict__ Wout,
                         float* __restrict__ out)
{
    const int t = blockIdx.x * blockDim.x + threadIdx.x;
    float be = 0.0f;
    for (int p = 0; p < 25; ++p) be += b1[p] * Wout[p];
    if (t < T_SEQ) out[t] = be;
}

extern "C" void kernel_launch(void* const* d_in, const int* in_sizes, int n_in,
                              void* d_out, int out_size, void* d_ws, size_t ws_size,
                              hipStream_t stream)
{
    const float* x    = (const float*)d_in[0];
    const float* W_ih = (const float*)d_in[1];
    const float* W_hh = (const float*)d_in[2];
    const float* b_ih = (const float*)d_in[3];
    const float* b_hh = (const float*)d_in[4];
    const float* W1   = (const float*)d_in[5];
    const float* b1   = (const float*)d_in[6];
    const float* Wout = (const float*)d_in[7];
    float* out = (float*)d_out;

    unsigned int* ctr  = (unsigned int*)d_ws;
    float*        hbuf = (float*)((char*)d_ws + 256);

    // zero barrier counter + both h buffers (ws is poisoned before each call)
    hipMemsetAsync(d_ws, 0, 256 + 2 * HID * sizeof(float), stream);
    init_out<<<(T_SEQ + 255) / 256, 256, 0, stream>>>(b1, Wout, out);
    lstm_persist<<<NWG, NTH, 0, stream>>>(x, W_ih, W_hh, b_ih, b_hh, W1, Wout,
                                          ctr, hbuf, out);
}

// Round 2
// 238844.263 us; speedup vs baseline: 2.1883x; 2.1883x over previous
//
#include <hip/hip_runtime.h>
#include <math.h>

// LSTM T=32768, B=1, I=128, H=512. Persistent kernel: 32 WGs x 512 threads,
// W_hh/W_ih register-resident, per-step global barrier via one LLC counter.
// R1 protocol fix: wave0-only RELAXED polling + per-thread acquire fence,
// float4 h-gather, release-add barrier arrival, fast exp-based activations.

#define T_SEQ 32768
#define HID   512
#define INP   128
#define NWG   32
#define NTH   512
#define HSL   16    // h elements per WG
#define KW    64    // W_hh weights per thread
#define KX    16    // W_ih weights per thread

__device__ __forceinline__ float fast_sigmoid(float x) {
    return 1.0f / (1.0f + __expf(-x));
}
__device__ __forceinline__ float fast_tanh(float x) {
    float a = fabsf(x);
    float e = __expf(-2.0f * a);          // underflows to 0 for large a -> r=1
    float r = (1.0f - e) / (1.0f + e);
    return copysignf(r, x);
}

__global__ void __launch_bounds__(NTH, 2) lstm_persist(
    const float* __restrict__ x,
    const float* __restrict__ W_ih,
    const float* __restrict__ W_hh,
    const float* __restrict__ b_ih,
    const float* __restrict__ b_hh,
    const float* __restrict__ W1,
    const float* __restrict__ Wout,
    unsigned int* __restrict__ ctr,
    float* __restrict__ hbuf,        // 2 * 512 floats, ping-pong (pre-zeroed)
    float* __restrict__ out)         // pre-initialized to b_eff
{
    const int w   = blockIdx.x;
    const int tid = threadIdx.x;
    const int rl  = tid >> 3;        // 0..63 local gate row
    const int j   = tid & 7;         // K-chunk
    const int gblk   = rl >> 4;      // 0..3 (i,f,g,o)
    const int within = rl & 15;
    const int grow   = gblk * HID + w * HSL + within;

    __shared__ float gate_lds[64];

    // ---- register-resident weights (loaded once) ----
    float wih[KX];
#pragma unroll
    for (int k = 0; k < KX; ++k) wih[k] = W_ih[grow * INP + j * KX + k];
    float whh[KW];
#pragma unroll
    for (int k = 0; k < KW; ++k) whh[k] = W_hh[grow * HID + j * KW + k];
    const float brow = b_ih[grow] + b_hh[grow];

    // fused output projection vector: w_eff[col] = sum_p Wout[p] * W1[p][col]
    float weff = 0.0f;
    if (tid < HSL) {
        const int col = w * HSL + tid;
        for (int p = 0; p < 25; ++p) weff += Wout[p] * W1[p * HID + col];
    }

    float c = 0.0f;

    // prefetch x_0 chunk
    float xa[KX];
#pragma unroll
    for (int k = 0; k < KX; ++k) xa[k] = x[j * KX + k];

    for (int t = 0; t < T_SEQ; ++t) {
        // ---- barrier: wave 0 polls (RELAXED — no invalidate per poll),
        //      syncthreads broadcasts, one acquire fence per thread ----
        if (tid < 64) {
            const unsigned int target = (unsigned int)NWG * (unsigned int)t;
            while (__hip_atomic_load(ctr, __ATOMIC_RELAXED,
                                     __HIP_MEMORY_SCOPE_AGENT) < target) {
                __builtin_amdgcn_s_sleep(1);
            }
        }
        __syncthreads();
        __builtin_amdgcn_fence(__ATOMIC_ACQUIRE, "agent");

        float a0 = 0.0f, a1 = 0.0f, a2 = 0.0f, a3 = 0.0f;

        // x contribution (x_t already in registers)
#pragma unroll
        for (int k = 0; k < KX; k += 4) {
            a0 += wih[k + 0] * xa[k + 0];
            a1 += wih[k + 1] * xa[k + 1];
            a2 += wih[k + 2] * xa[k + 2];
            a3 += wih[k + 3] * xa[k + 3];
        }

        // h gather: plain float4 loads (fresh past the acquire fence)
        const float4* hb4 =
            (const float4*)(hbuf + (t & 1) * HID) + j * (KW / 4);
#pragma unroll
        for (int k = 0; k < KW / 4; ++k) {
            const float4 h4 = hb4[k];
            a0 += whh[4 * k + 0] * h4.x;
            a1 += whh[4 * k + 1] * h4.y;
            a2 += whh[4 * k + 2] * h4.z;
            a3 += whh[4 * k + 3] * h4.w;
        }

        // prefetch x_{t+1} (off critical path)
        const int tn = (t + 1 < T_SEQ) ? (t + 1) : t;
#pragma unroll
        for (int k = 0; k < KX; k += 4) {
            const float4 x4 = *(const float4*)&x[tn * INP + j * KX + k];
            xa[k + 0] = x4.x; xa[k + 1] = x4.y;
            xa[k + 2] = x4.z; xa[k + 3] = x4.w;
        }

        float acc = (a0 + a1) + (a2 + a3);
        acc += __shfl_xor(acc, 1);
        acc += __shfl_xor(acc, 2);
        acc += __shfl_xor(acc, 4);
        if (j == 0) gate_lds[rl] = acc + brow;
        __syncthreads();

        float hv = 0.0f;
        if (tid < HSL) {
            const float ig = gate_lds[tid];
            const float fg = gate_lds[16 + tid];
            const float gg = gate_lds[32 + tid];
            const float og = gate_lds[48 + tid];
            const float iv = fast_sigmoid(ig);
            const float fv = fast_sigmoid(fg);
            const float gv = fast_tanh(gg);
            const float ov = fast_sigmoid(og);
            c = fv * c + iv * gv;
            hv = ov * fast_tanh(c);
            __hip_atomic_store(&hbuf[((t + 1) & 1) * HID + w * HSL + tid], hv,
                               __ATOMIC_RELAXED, __HIP_MEMORY_SCOPE_AGENT);
        }
        // release: waits vmcnt(0) (covers wave0's h stores) + L2 writeback
        if (tid == 0)
            __hip_atomic_fetch_add(ctr, 1u, __ATOMIC_RELEASE,
                                   __HIP_MEMORY_SCOPE_AGENT);
        // fused output projection partial — AFTER arrival, off critical path
        if (tid < HSL) {
            float pd = hv * weff;
            pd += __shfl_xor(pd, 1);
            pd += __shfl_xor(pd, 2);
            pd += __shfl_xor(pd, 4);
            pd += __shfl_xor(pd, 8);
            if (tid == 0) atomicAdd(&out[t], pd);
        }
    }
}

// out[t] starts at b_eff = dot(b1, Wout); persistent kernel atomicAdds the
// h-projection partials on top.
__global__ void init_out(const float* __restrict__ b1,
                         const float* __restrict__ Wout,
                         float* __restrict__ out)
{
    const int t = blockIdx.x * blockDim.x + threadIdx.x;
    float be = 0.0f;
    for (int p = 0; p < 25; ++p) be += b1[p] * Wout[p];
    if (t < T_SEQ) out[t] = be;
}

extern "C" void kernel_launch(void* const* d_in, const int* in_sizes, int n_in,
                              void* d_out, int out_size, void* d_ws, size_t ws_size,
                              hipStream_t stream)
{
    const float* x    = (const float*)d_in[0];
    const float* W_ih = (const float*)d_in[1];
    const float* W_hh = (const float*)d_in[2];
    const float* b_ih = (const float*)d_in[3];
    const float* b_hh = (const float*)d_in[4];
    const float* W1   = (const float*)d_in[5];
    const float* b1   = (const float*)d_in[6];
    const float* Wout = (const float*)d_in[7];
    float* out = (float*)d_out;

    unsigned int* ctr  = (unsigned int*)d_ws;
    float*        hbuf = (float*)((char*)d_ws + 256);

    // zero barrier counter + both h buffers (ws is poisoned before each call)
    hipMemsetAsync(d_ws, 0, 256 + 2 * HID * sizeof(float), stream);
    init_out<<<(T_SEQ + 255) / 256, 256, 0, stream>>>(b1, Wout, out);
    lstm_persist<<<NWG, NTH, 0, stream>>>(x, W_ih, W_hh, b_ih, b_hh, W1, Wout,
                                          ctr, hbuf, out);
}